// Round 1
// baseline (1398.432 us; speedup 1.0000x reference)
//
#include <hip/hip_runtime.h>
#include <hip/hip_bf16.h>

// ---------------------------------------------------------------------------
// ALiBi MHA, windowed (window/2 = 128 keys each side), B=2 T=2048 D=1024 H=16
// Round 0: correct fp32 baseline.
//   - gemm_nt: C[m][n] = sum_k A[m][k]*B[n][k]  (both row-major, K contiguous)
//     optional permute to (B,H,T,dk) layout for Q/K/V.
//   - attn_kernel: 1 wave per query row; windowed softmax with ALiBi;
//     writes attn probs (in-window) + attention output (B,T,D).
//   - memset zeroes the out-of-window attn region every call (reference has
//     exact zeros there: softmax of -inf).
// ---------------------------------------------------------------------------

__global__ __launch_bounds__(256) void gemm_nt_kernel(
    const float* __restrict__ A, const float* __restrict__ B,
    float* __restrict__ C, int M, int N, int K, int permT /*0 = plain*/)
{
    __shared__ float As[16][65];
    __shared__ float Bs[16][65];
    const int bm = blockIdx.y * 64;
    const int bn = blockIdx.x * 64;
    const int tid = threadIdx.x;
    const int tx = tid & 15, ty = tid >> 4;

    float acc[4][4] = {};

    for (int k0 = 0; k0 < K; k0 += 16) {
#pragma unroll
        for (int l = 0; l < 4; ++l) {
            int idx = tid + l * 256;          // 0..1023
            int r = idx >> 4, kk = idx & 15;
            As[kk][r] = A[(size_t)(bm + r) * K + (k0 + kk)];
            Bs[kk][r] = B[(size_t)(bn + r) * K + (k0 + kk)];
        }
        __syncthreads();
#pragma unroll
        for (int kk = 0; kk < 16; ++kk) {
            float a[4], b[4];
#pragma unroll
            for (int i = 0; i < 4; ++i) a[i] = As[kk][ty * 4 + i];
#pragma unroll
            for (int j = 0; j < 4; ++j) b[j] = Bs[kk][tx * 4 + j];
#pragma unroll
            for (int i = 0; i < 4; ++i)
#pragma unroll
                for (int j = 0; j < 4; ++j)
                    acc[i][j] += a[i] * b[j];
        }
        __syncthreads();
    }

#pragma unroll
    for (int i = 0; i < 4; ++i) {
        int m = bm + ty * 4 + i;
#pragma unroll
        for (int j = 0; j < 4; ++j) {
            int n = bn + tx * 4 + j;
            size_t off;
            if (permT) {
                // output layout (B, H, T, 64): m = b*T + t, n = h*64 + dd
                int b = m / permT;
                int t = m - b * permT;
                int h = n >> 6;
                int dd = n & 63;
                off = (((size_t)b * 16 + h) * (size_t)permT + t) * 64 + dd;
            } else {
                off = (size_t)m * N + n;
            }
            C[off] = acc[i][j];
        }
    }
}

// One wave (64 lanes) per query row. Q/K/V in (B,H,T,64) layout.
__global__ __launch_bounds__(256) void attn_kernel(
    const float* __restrict__ Q, const float* __restrict__ K,
    const float* __restrict__ V, float* __restrict__ attn,
    float* __restrict__ ao, const int* __restrict__ wptr,
    int B, int H, int T)
{
    const int w    = threadIdx.x >> 6;
    const int lane = threadIdx.x & 63;
    const int qid  = blockIdx.x * 4 + w;          // (b*H + h)*T + t
    const int t = qid % T;
    const int h = (qid / T) % H;
    const int b = qid / (T * H);

    const int W2 = wptr[0] / 2;                   // 128
    int s0 = t - W2; if (s0 < 0) s0 = 0;
    int s1 = t + W2; if (s1 > T - 1) s1 = T - 1;
    const int cnt = s1 - s0 + 1;                  // <= 257

    __shared__ float qs[4][64];
    __shared__ float ps[4][260];

    const size_t bh = ((size_t)b * H + h) * (size_t)T;
    qs[w][lane] = Q[(bh + t) * 64 + lane];
    __syncthreads();

    const float slope = exp2f(-0.5f * (float)(h + 1));

    // phase 1: scores (each lane owns keys s0+lane, s0+lane+64, ...)
    float sc[5];
    int nk = 0;
    float mval = -1e30f;
    for (int i = lane; i < cnt; i += 64) {
        const int s = s0 + i;
        const float4* k4 = (const float4*)(K + (bh + s) * 64);
        float d = 0.f;
#pragma unroll
        for (int dd = 0; dd < 16; ++dd) {
            float4 kv = k4[dd];
            d += qs[w][4 * dd + 0] * kv.x + qs[w][4 * dd + 1] * kv.y +
                 qs[w][4 * dd + 2] * kv.z + qs[w][4 * dd + 3] * kv.w;
        }
        float v = d * 0.125f - slope * fabsf((float)(t - s));
        sc[nk++] = v;
        if (v > mval) mval = v;
    }

    // phase 2: wave softmax
#pragma unroll
    for (int off = 32; off; off >>= 1) {
        float o = __shfl_xor(mval, off, 64);
        if (o > mval) mval = o;
    }
    float lsum = 0.f;
    for (int i = 0; i < nk; ++i) { sc[i] = expf(sc[i] - mval); lsum += sc[i]; }
#pragma unroll
    for (int off = 32; off; off >>= 1) lsum += __shfl_xor(lsum, off, 64);
    const float inv = 1.0f / lsum;

    // phase 3: write attn probs + stash in LDS
    float* arow = attn + (bh + t) * (size_t)T;
    {
        int idx = lane;
        for (int i = 0; i < nk; ++i, idx += 64) {
            float p = sc[i] * inv;
            arow[s0 + idx] = p;
            ps[w][idx] = p;
        }
    }
    __syncthreads();

    // phase 4: PV — lane owns output dim d = lane
    float acc = 0.f;
    const float* vbase = V + (bh + s0) * 64 + lane;
    for (int i = 0; i < cnt; ++i) acc += ps[w][i] * vbase[(size_t)i * 64];

    ao[((size_t)b * T + t) * (size_t)(H * 64) + h * 64 + lane] = acc;
}

extern "C" void kernel_launch(void* const* d_in, const int* in_sizes, int n_in,
                              void* d_out, int out_size, void* d_ws, size_t ws_size,
                              hipStream_t stream)
{
    const float* x  = (const float*)d_in[0];
    const float* Wq = (const float*)d_in[1];
    const float* Wk = (const float*)d_in[2];
    const float* Wv = (const float*)d_in[3];
    const float* Wo = (const float*)d_in[4];
    const int*  win = (const int*)d_in[5];

    const int B = 2, T = 2048, D = 1024, H = 16;
    const int M = B * T;                              // 4096

    float* Qb = (float*)d_ws;
    float* Kb = Qb + (size_t)M * D;
    float* Vb = Kb + (size_t)M * D;
    float* AO = Vb + (size_t)M * D;                   // total 64 MB

    float* out  = (float*)d_out;                      // (B,T,D)
    float* attn = out + (size_t)M * D;                // (B,H,T,T)

    dim3 gg(D / 64, M / 64);
    gemm_nt_kernel<<<gg, 256, 0, stream>>>(x, Wq, Qb, M, D, D, T);
    gemm_nt_kernel<<<gg, 256, 0, stream>>>(x, Wk, Kb, M, D, D, T);
    gemm_nt_kernel<<<gg, 256, 0, stream>>>(x, Wv, Vb, M, D, D, T);

    hipMemsetAsync(attn, 0, (size_t)B * H * T * (size_t)T * sizeof(float), stream);

    attn_kernel<<<(B * H * T) / 4, 256, 0, stream>>>(Qb, Kb, Vb, attn, AO, win, B, H, T);

    gemm_nt_kernel<<<gg, 256, 0, stream>>>(AO, Wo, out, M, D, D, 0);
}

// Round 2
// 567.379 us; speedup vs baseline: 2.4647x; 2.4647x over previous
//
#include <hip/hip_runtime.h>
#include <hip/hip_bf16.h>

// ---------------------------------------------------------------------------
// ALiBi MHA, windowed. B=2 T=2048 D=1024 H=16 d_k=64, window/2=128.
// Round 1: bf16 MFMA GEMMs (fused QKV), register-Q attn, fused zero-fill.
// ---------------------------------------------------------------------------

typedef __bf16 bf16x8 __attribute__((ext_vector_type(8)));
typedef float f32x4 __attribute__((ext_vector_type(4)));
typedef unsigned short u16x8 __attribute__((ext_vector_type(8)));

__device__ __forceinline__ float bf2f(unsigned short u) {
    union { unsigned int i; float f; } v; v.i = ((unsigned int)u) << 16; return v.f;
}
__device__ __forceinline__ unsigned short f2bf(float f) {
    union { float f; unsigned int i; } v; v.f = f;
    unsigned int r = v.i + 0x7FFFu + ((v.i >> 16) & 1u);
    return (unsigned short)(r >> 16);
}

__global__ __launch_bounds__(256) void cast_kernel(const float* __restrict__ in,
                                                   unsigned short* __restrict__ out, int n) {
    int i = (blockIdx.x * 256 + threadIdx.x) * 4;
    if (i < n) {
        const float4 v = *(const float4*)(in + i);
        ushort4 o;
        o.x = f2bf(v.x); o.y = f2bf(v.y); o.z = f2bf(v.z); o.w = f2bf(v.w);
        *(ushort4*)(out + i) = o;
    }
}

#define GLDS16(g, l) __builtin_amdgcn_global_load_lds(                      \
    (const __attribute__((address_space(1))) void*)(g),                     \
    (__attribute__((address_space(3))) void*)(l), 16, 0, 0)

// C = A (MxK) * Bm^T (NxK); bf16 in, fp32 accum.
// mode 0: C fp32 row-major. mode 1: scatter to per-head bf16 QKV layout.
__global__ __launch_bounds__(256) void gemm_bf16_nt(
    const unsigned short* __restrict__ A, const unsigned short* __restrict__ Bm,
    float* __restrict__ C, unsigned short* __restrict__ qkv,
    int M, int N, int K, int mode)
{
    __shared__ __align__(16) unsigned short As[128 * 32];
    __shared__ __align__(16) unsigned short Bs[128 * 32];

    const int tid  = threadIdx.x;
    const int lane = tid & 63, w = tid >> 6;
    const int bm = blockIdx.y * 128, bn = blockIdx.x * 128;

    const unsigned short* ga = A  + (size_t)(bm + w * 16 + (lane >> 2)) * K + (lane & 3) * 8;
    const unsigned short* gb = Bm + (size_t)(bn + w * 16 + (lane >> 2)) * K + (lane & 3) * 8;
    unsigned short* laA0 = &As[w * 512];
    unsigned short* laA1 = &As[2048 + w * 512];
    unsigned short* laB0 = &Bs[w * 512];
    unsigned short* laB1 = &Bs[2048 + w * 512];

    const int wr = w >> 1, wc = w & 1;
    const int fr = lane & 15, fq = lane >> 4;

    f32x4 acc[4][4] = {};

    for (int k0 = 0; k0 < K; k0 += 32) {
        GLDS16(ga + k0, laA0);
        GLDS16(ga + k0 + (size_t)64 * K, laA1);
        GLDS16(gb + k0, laB0);
        GLDS16(gb + k0 + (size_t)64 * K, laB1);
        __syncthreads();
        bf16x8 af[4], bfv[4];
#pragma unroll
        for (int i = 0; i < 4; ++i)
            af[i] = *(const bf16x8*)&As[(wr * 64 + i * 16 + fr) * 32 + fq * 8];
#pragma unroll
        for (int j = 0; j < 4; ++j)
            bfv[j] = *(const bf16x8*)&Bs[(wc * 64 + j * 16 + fr) * 32 + fq * 8];
#pragma unroll
        for (int i = 0; i < 4; ++i)
#pragma unroll
            for (int j = 0; j < 4; ++j)
                acc[i][j] = __builtin_amdgcn_mfma_f32_16x16x32_bf16(af[i], bfv[j], acc[i][j], 0, 0, 0);
        __syncthreads();
    }

#pragma unroll
    for (int i = 0; i < 4; ++i) {
#pragma unroll
        for (int j = 0; j < 4; ++j) {
            const int mb = bm + wr * 64 + i * 16 + fq * 4;
            const int n  = bn + wc * 64 + j * 16 + fr;
#pragma unroll
            for (int r = 0; r < 4; ++r) {
                const int m = mb + r;
                const float val = acc[i][j][r];
                if (mode == 0) {
                    C[(size_t)m * N + n] = val;
                } else {
                    // n in [0,3072): which = q/k/v, h = head, dd = dim
                    const int which = n >> 10, h = (n >> 6) & 15, dd = n & 63;
                    const int b = m >> 11, t = m & 2047;
                    qkv[(size_t)which * 4194304 +
                        (((size_t)b * 16 + h) * 2048 + t) * 64 + dd] = f2bf(val);
                }
            }
        }
    }
}

// One wave per query row. Q/K/V bf16 in (B,H,T,64) layout.
// Writes full attn prob rows (incl. zeros) + bf16 attention output.
__global__ __launch_bounds__(256) void attn_kernel(
    const unsigned short* __restrict__ Q, const unsigned short* __restrict__ K,
    const unsigned short* __restrict__ V, float* __restrict__ attn,
    unsigned short* __restrict__ ao, const int* __restrict__ wptr)
{
    const int T = 2048, H = 16;
    const int w = threadIdx.x >> 6, lane = threadIdx.x & 63;
    const int qid = blockIdx.x * 4 + w;
    const int t = qid & (T - 1);
    const int h = (qid >> 11) & (H - 1);
    const int b = qid >> 15;

    const int W2 = wptr[0] >> 1;
    int s0 = t - W2; if (s0 < 0) s0 = 0;
    int s1 = t + W2; if (s1 > T - 1) s1 = T - 1;
    const int cnt = s1 - s0 + 1;               // 129..257

    __shared__ float ps[4][260];

    const size_t bh = ((size_t)b * H + h) * T;

    // Q row -> registers (fp32)
    float q[64];
    {
        const unsigned short* qrow = Q + (bh + t) * 64;
#pragma unroll
        for (int c = 0; c < 8; ++c) {
            u16x8 v = *(const u16x8*)(qrow + c * 8);
#pragma unroll
            for (int e = 0; e < 8; ++e) q[c * 8 + e] = bf2f(v[e]);
        }
    }

    const float slope = exp2f(-0.5f * (float)(h + 1));

    // scores: fixed 5 strided keys per lane (static indexing)
    float sc[5];
    float mval = -1e30f;
#pragma unroll
    for (int j = 0; j < 5; ++j) {
        const int i = lane + j * 64;
        const bool valid = i < cnt;
        const int s = s0 + (valid ? i : 0);
        const unsigned short* krow = K + (bh + s) * 64;
        float d0 = 0.f, d1 = 0.f, d2 = 0.f, d3 = 0.f;
#pragma unroll
        for (int c = 0; c < 8; ++c) {
            u16x8 kv = *(const u16x8*)(krow + c * 8);
            d0 += q[c * 8 + 0] * bf2f(kv[0]); d1 += q[c * 8 + 1] * bf2f(kv[1]);
            d2 += q[c * 8 + 2] * bf2f(kv[2]); d3 += q[c * 8 + 3] * bf2f(kv[3]);
            d0 += q[c * 8 + 4] * bf2f(kv[4]); d1 += q[c * 8 + 5] * bf2f(kv[5]);
            d2 += q[c * 8 + 6] * bf2f(kv[6]); d3 += q[c * 8 + 7] * bf2f(kv[7]);
        }
        const float d = (d0 + d1) + (d2 + d3);
        const float v = valid ? (d * 0.125f - slope * fabsf((float)(t - s))) : -1e30f;
        sc[j] = v;
        mval = fmaxf(mval, v);
    }

    // wave softmax
#pragma unroll
    for (int off = 32; off; off >>= 1) mval = fmaxf(mval, __shfl_xor(mval, off, 64));
    float lsum = 0.f;
#pragma unroll
    for (int j = 0; j < 5; ++j) { sc[j] = __expf(sc[j] - mval); lsum += sc[j]; }
#pragma unroll
    for (int off = 32; off; off >>= 1) lsum += __shfl_xor(lsum, off, 64);
    const float inv = 1.0f / lsum;

#pragma unroll
    for (int j = 0; j < 5; ++j) {
        const int i = lane + j * 64;
        if (i < cnt) ps[w][i] = sc[j] * inv;
    }
    __syncthreads();

    // full-row prob write (zeros outside window) — replaces the 512MB memset
    float* arow = attn + (bh + t) * (size_t)T;
#pragma unroll
    for (int jj = 0; jj < 32; ++jj) {
        const int col = lane + jj * 64;
        int ii = col - s0;
        ii = ii < 0 ? 0 : (ii >= cnt ? cnt - 1 : ii);
        const float pv = ps[w][ii];
        arow[col] = (col >= s0 && col <= s1) ? pv : 0.f;
    }

    // PV: lane owns output dim = lane; 4 independent chains
    const unsigned short* vb = V + (bh + s0) * 64 + lane;
    float a0 = 0.f, a1 = 0.f, a2 = 0.f, a3 = 0.f;
    int i = 0;
    for (; i + 4 <= cnt; i += 4) {
        a0 += ps[w][i + 0] * bf2f(vb[(size_t)(i + 0) * 64]);
        a1 += ps[w][i + 1] * bf2f(vb[(size_t)(i + 1) * 64]);
        a2 += ps[w][i + 2] * bf2f(vb[(size_t)(i + 2) * 64]);
        a3 += ps[w][i + 3] * bf2f(vb[(size_t)(i + 3) * 64]);
    }
    for (; i < cnt; ++i) a0 += ps[w][i] * bf2f(vb[(size_t)i * 64]);
    const float o = (a0 + a1) + (a2 + a3);

    ao[((size_t)b * T + t) * 1024 + h * 64 + lane] = f2bf(o);
}

extern "C" void kernel_launch(void* const* d_in, const int* in_sizes, int n_in,
                              void* d_out, int out_size, void* d_ws, size_t ws_size,
                              hipStream_t stream)
{
    const float* x  = (const float*)d_in[0];
    const float* Wq = (const float*)d_in[1];
    const float* Wk = (const float*)d_in[2];
    const float* Wv = (const float*)d_in[3];
    const float* Wo = (const float*)d_in[4];
    const int*  win = (const int*)d_in[5];

    const int M = 4096, D = 1024;                 // M = B*T

    unsigned short* xb    = (unsigned short*)d_ws;            // 4096x1024
    unsigned short* Wqkvb = xb + (size_t)M * D;               // 3072x1024
    unsigned short* Wob   = Wqkvb + (size_t)3 * D * D;        // 1024x1024
    unsigned short* QKVb  = Wob + (size_t)D * D;              // 3 x (B,H,T,64)
    unsigned short* AOb   = QKVb + (size_t)3 * M * D;         // 4096x1024
    // total: (4+3+1+12+4) M elems * 2B = 48 MB

    float* out  = (float*)d_out;                  // (B,T,D)
    float* attn = out + (size_t)M * D;            // (B,H,T,T)

    cast_kernel<<<M * D / 1024, 256, 0, stream>>>(x, xb, M * D);
    cast_kernel<<<D * D / 1024, 256, 0, stream>>>(Wq, Wqkvb, D * D);
    cast_kernel<<<D * D / 1024, 256, 0, stream>>>(Wk, Wqkvb + (size_t)D * D, D * D);
    cast_kernel<<<D * D / 1024, 256, 0, stream>>>(Wv, Wqkvb + (size_t)2 * D * D, D * D);
    cast_kernel<<<D * D / 1024, 256, 0, stream>>>(Wo, Wob, D * D);

    {
        dim3 g(3072 / 128, M / 128);
        gemm_bf16_nt<<<g, 256, 0, stream>>>(xb, Wqkvb, nullptr, QKVb, M, 3072, D, 1);
    }

    attn_kernel<<<(2 * 16 * 2048) / 4, 256, 0, stream>>>(
        QKVb, QKVb + (size_t)M * D, QKVb + (size_t)2 * M * D, attn, AOb, win);

    {
        dim3 g(D / 128, M / 128);
        gemm_bf16_nt<<<g, 256, 0, stream>>>(AOb, Wob, out, nullptr, M, D, D, 0);
    }
}

// Round 3
// 238.592 us; speedup vs baseline: 5.8612x; 2.3780x over previous
//
#include <hip/hip_runtime.h>
#include <hip/hip_bf16.h>

// ---------------------------------------------------------------------------
// ALiBi MHA, windowed. B=2 T=2048 D=1024 H=16 d_k=64, window/2=128.
// Round 2: MFMA attention (QK^T + PV on matrix cores), V stored transposed,
// per-wave-private LDS P transpose, no barriers, XCD swizzle.
// ---------------------------------------------------------------------------

typedef __bf16 bf16x8 __attribute__((ext_vector_type(8)));
typedef float f32x4 __attribute__((ext_vector_type(4)));

__device__ __forceinline__ unsigned short f2bf(float f) {
    union { float f; unsigned int i; } v; v.f = f;
    unsigned int r = v.i + 0x7FFFu + ((v.i >> 16) & 1u);
    return (unsigned short)(r >> 16);
}

__global__ __launch_bounds__(256) void cast_kernel(const float* __restrict__ in,
                                                   unsigned short* __restrict__ out, int n) {
    int i = (blockIdx.x * 256 + threadIdx.x) * 4;
    if (i < n) {
        const float4 v = *(const float4*)(in + i);
        ushort4 o;
        o.x = f2bf(v.x); o.y = f2bf(v.y); o.z = f2bf(v.z); o.w = f2bf(v.w);
        *(ushort4*)(out + i) = o;
    }
}

#define GLDS16(g, l) __builtin_amdgcn_global_load_lds(                      \
    (const __attribute__((address_space(1))) void*)(g),                     \
    (__attribute__((address_space(3))) void*)(l), 16, 0, 0)

// C = A (MxK) * Bm^T (NxK); bf16 in, fp32 accum.
// mode 0: C fp32 row-major. mode 1: scatter bf16 QKV; V goes out TRANSPOSED
// as (B,H,64,T) so the attention PV step can load V^T rows directly.
__global__ __launch_bounds__(256) void gemm_bf16_nt(
    const unsigned short* __restrict__ A, const unsigned short* __restrict__ Bm,
    float* __restrict__ C, unsigned short* __restrict__ qkv,
    int M, int N, int K, int mode)
{
    __shared__ __align__(16) unsigned short As[128 * 32];
    __shared__ __align__(16) unsigned short Bs[128 * 32];

    const int tid  = threadIdx.x;
    const int lane = tid & 63, w = tid >> 6;
    const int bm = blockIdx.y * 128, bn = blockIdx.x * 128;

    const unsigned short* ga = A  + (size_t)(bm + w * 16 + (lane >> 2)) * K + (lane & 3) * 8;
    const unsigned short* gb = Bm + (size_t)(bn + w * 16 + (lane >> 2)) * K + (lane & 3) * 8;
    unsigned short* laA0 = &As[w * 512];
    unsigned short* laA1 = &As[2048 + w * 512];
    unsigned short* laB0 = &Bs[w * 512];
    unsigned short* laB1 = &Bs[2048 + w * 512];

    const int wr = w >> 1, wc = w & 1;
    const int fr = lane & 15, fq = lane >> 4;

    f32x4 acc[4][4] = {};

    for (int k0 = 0; k0 < K; k0 += 32) {
        GLDS16(ga + k0, laA0);
        GLDS16(ga + k0 + (size_t)64 * K, laA1);
        GLDS16(gb + k0, laB0);
        GLDS16(gb + k0 + (size_t)64 * K, laB1);
        __syncthreads();
        bf16x8 af[4], bfv[4];
#pragma unroll
        for (int i = 0; i < 4; ++i)
            af[i] = *(const bf16x8*)&As[(wr * 64 + i * 16 + fr) * 32 + fq * 8];
#pragma unroll
        for (int j = 0; j < 4; ++j)
            bfv[j] = *(const bf16x8*)&Bs[(wc * 64 + j * 16 + fr) * 32 + fq * 8];
#pragma unroll
        for (int i = 0; i < 4; ++i)
#pragma unroll
            for (int j = 0; j < 4; ++j)
                acc[i][j] = __builtin_amdgcn_mfma_f32_16x16x32_bf16(af[i], bfv[j], acc[i][j], 0, 0, 0);
        __syncthreads();
    }

#pragma unroll
    for (int i = 0; i < 4; ++i) {
#pragma unroll
        for (int j = 0; j < 4; ++j) {
            const int mb = bm + wr * 64 + i * 16 + fq * 4;
            const int n  = bn + wc * 64 + j * 16 + fr;
#pragma unroll
            for (int r = 0; r < 4; ++r) {
                const int m = mb + r;
                const float val = acc[i][j][r];
                if (mode == 0) {
                    C[(size_t)m * N + n] = val;
                } else {
                    const int which = n >> 10, hh = (n >> 6) & 15, dd = n & 63;
                    const int bb = m >> 11, tt = m & 2047;
                    size_t off;
                    if (which == 2)   // V transposed: (B,H,64,T)
                        off = (size_t)2 * 4194304 + (((size_t)bb * 16 + hh) * 64 + dd) * 2048 + tt;
                    else
                        off = (size_t)which * 4194304 + (((size_t)bb * 16 + hh) * 2048 + tt) * 64 + dd;
                    qkv[off] = f2bf(val);
                }
            }
        }
    }
}

// MFMA attention. Block = 64 q-rows of one head; 4 waves x 16 q-rows.
// Q,K bf16 (B,H,T,64); VT bf16 (B,H,64,T). Writes full fp32 prob rows
// (zeros outside window) and bf16 attention output (B,T,H*64).
#define NT_MAX 20
__global__ __launch_bounds__(256) void attn_mfma(
    const unsigned short* __restrict__ Q, const unsigned short* __restrict__ K,
    const unsigned short* __restrict__ VT, float* __restrict__ attn,
    unsigned short* __restrict__ ao, const int* __restrict__ wptr)
{
    const int T = 2048;
    __shared__ __align__(16) unsigned short Plds[4][16][328];

    const int bid = (int)blockIdx.x;
    const int swz = (bid & 7) * 128 + (bid >> 3);      // XCD-contiguous
    const int w = threadIdx.x >> 6, lane = threadIdx.x & 63;
    const int fr = lane & 15, fq = lane >> 4;

    const int tblk = swz & 31;
    const int h    = (swz >> 5) & 15;
    const int b    = swz >> 9;
    const int t0   = tblk * 64;

    const int W2 = wptr[0] >> 1;                       // 128 (mult of 16)
    const int sA = (t0 - W2) > 0 ? (t0 - W2) : 0;
    int sB = t0 + 63 + W2; if (sB > T - 1) sB = T - 1;
    const int nt  = (sB + 1 - sA) >> 4;                // 12..20 tiles
    const int ncc = nt >> 1;                           // 32-wide PV chunks

    const size_t bhT = ((size_t)b * 16 + h) * T;
    const unsigned short* Qbh  = Q  + bhT * 64;
    const unsigned short* Kbh  = K  + bhT * 64;
    const unsigned short* VTbh = VT + (((size_t)b * 16 + h) * 64) * T;

    // ---- zero-fill outside [sA, sB] (streams while compute runs) ----
    {
        const float4 z4 = {0.f, 0.f, 0.f, 0.f};
        for (int i = 0; i < 16; ++i) {
            float* row = attn + (bhT + t0 + w * 16 + i) * T;
            for (int c = lane * 4; c < sA; c += 256) *(float4*)(row + c) = z4;
            for (int c = sB + 1 + lane * 4; c < T; c += 256) *(float4*)(row + c) = z4;
        }
    }

    // ---- Q fragments (16 rows x 64) ----
    bf16x8 aq0 = *(const bf16x8*)(Qbh + (size_t)(t0 + w * 16 + fr) * 64 + fq * 8);
    bf16x8 aq1 = *(const bf16x8*)(Qbh + (size_t)(t0 + w * 16 + fr) * 64 + 32 + fq * 8);

    const float slope = exp2f(-0.5f * (float)(h + 1));
    const int trow0 = t0 + w * 16 + fq * 4;

    // ---- QK^T: 20 tiles of 16 keys ----
    f32x4 sc[NT_MAX];
#pragma unroll
    for (int st = 0; st < NT_MAX; ++st) {
        const int sbase = sA + st * 16;
        if (sbase <= sB) {
            const unsigned short* kb = Kbh + (size_t)(sbase + fr) * 64 + fq * 8;
            bf16x8 b0 = *(const bf16x8*)(kb);
            bf16x8 b1 = *(const bf16x8*)(kb + 32);
            f32x4 sv = {0.f, 0.f, 0.f, 0.f};
            sv = __builtin_amdgcn_mfma_f32_16x16x32_bf16(aq0, b0, sv, 0, 0, 0);
            sv = __builtin_amdgcn_mfma_f32_16x16x32_bf16(aq1, b1, sv, 0, 0, 0);
            const int scol = sbase + fr;
#pragma unroll
            for (int rr = 0; rr < 4; ++rr) {
                const int d = trow0 + rr - scol;
                const int ad = d < 0 ? -d : d;
                const float val = sv[rr] * 0.125f - slope * (float)ad;
                sc[st][rr] = (ad <= W2) ? val : -1e30f;
            }
        } else {
            sc[st] = (f32x4){-1e30f, -1e30f, -1e30f, -1e30f};
        }
    }

    // ---- softmax per row (row spread over 16 fr-lanes) ----
    float inv[4];
#pragma unroll
    for (int rr = 0; rr < 4; ++rr) {
        float m = -1e30f;
#pragma unroll
        for (int st = 0; st < NT_MAX; ++st) m = fmaxf(m, sc[st][rr]);
#pragma unroll
        for (int off = 1; off < 16; off <<= 1) m = fmaxf(m, __shfl_xor(m, off, 64));
        float s = 0.f;
#pragma unroll
        for (int st = 0; st < NT_MAX; ++st) {
            const float p = __expf(sc[st][rr] - m);
            sc[st][rr] = p;
            s += p;
        }
#pragma unroll
        for (int off = 1; off < 16; off <<= 1) s += __shfl_xor(s, off, 64);
        inv[rr] = 1.0f / s;
    }

    // ---- prob writes (fp32 global) + bf16 LDS transpose stage ----
#pragma unroll
    for (int st = 0; st < NT_MAX; ++st) {
        const int sbase = sA + st * 16;
        if (sbase <= sB) {
            const int scol = sbase + fr;
#pragma unroll
            for (int rr = 0; rr < 4; ++rr) {
                const float p = sc[st][rr] * inv[rr];
                attn[(bhT + trow0 + rr) * T + scol] = p;
                Plds[w][fq * 4 + rr][st * 16 + fr] = f2bf(p);
            }
        } else {
#pragma unroll
            for (int rr = 0; rr < 4; ++rr)
                Plds[w][fq * 4 + rr][st * 16 + fr] = 0;
        }
    }

    // ---- PV: out[16q x 64d] = P[16 x 320] x V[320 x 64] ----
    f32x4 oacc[4] = {};
    for (int c = 0; c < ncc; ++c) {
        const bf16x8 pa = *(const bf16x8*)&Plds[w][fr][c * 32 + fq * 8];
#pragma unroll
        for (int j = 0; j < 4; ++j) {
            const bf16x8 bv = *(const bf16x8*)(VTbh + (size_t)(j * 16 + fr) * T + sA + c * 32 + fq * 8);
            oacc[j] = __builtin_amdgcn_mfma_f32_16x16x32_bf16(pa, bv, oacc[j], 0, 0, 0);
        }
    }

#pragma unroll
    for (int j = 0; j < 4; ++j)
#pragma unroll
        for (int rr = 0; rr < 4; ++rr)
            ao[((size_t)b * T + trow0 + rr) * 1024 + h * 64 + j * 16 + fr] = f2bf(oacc[j][rr]);
}

extern "C" void kernel_launch(void* const* d_in, const int* in_sizes, int n_in,
                              void* d_out, int out_size, void* d_ws, size_t ws_size,
                              hipStream_t stream)
{
    const float* x  = (const float*)d_in[0];
    const float* Wq = (const float*)d_in[1];
    const float* Wk = (const float*)d_in[2];
    const float* Wv = (const float*)d_in[3];
    const float* Wo = (const float*)d_in[4];
    const int*  win = (const int*)d_in[5];

    const int M = 4096, D = 1024;                 // M = B*T

    unsigned short* xb    = (unsigned short*)d_ws;            // 4096x1024
    unsigned short* Wqkvb = xb + (size_t)M * D;               // 3072x1024
    unsigned short* Wob   = Wqkvb + (size_t)3 * D * D;        // 1024x1024
    unsigned short* QKVb  = Wob + (size_t)D * D;              // Q,K,(V^T)
    unsigned short* AOb   = QKVb + (size_t)3 * M * D;         // 4096x1024

    float* out  = (float*)d_out;                  // (B,T,D)
    float* attn = out + (size_t)M * D;            // (B,H,T,T)

    cast_kernel<<<M * D / 1024, 256, 0, stream>>>(x, xb, M * D);
    cast_kernel<<<D * D / 1024, 256, 0, stream>>>(Wq, Wqkvb, D * D);
    cast_kernel<<<D * D / 1024, 256, 0, stream>>>(Wk, Wqkvb + (size_t)D * D, D * D);
    cast_kernel<<<D * D / 1024, 256, 0, stream>>>(Wv, Wqkvb + (size_t)2 * D * D, D * D);
    cast_kernel<<<D * D / 1024, 256, 0, stream>>>(Wo, Wob, D * D);

    {
        dim3 g(3072 / 128, M / 128);
        gemm_bf16_nt<<<g, 256, 0, stream>>>(xb, Wqkvb, nullptr, QKVb, M, 3072, D, 1);
    }

    attn_mfma<<<1024, 256, 0, stream>>>(
        QKVb, QKVb + (size_t)M * D, QKVb + (size_t)2 * M * D, attn, AOb, win);

    {
        dim3 g(D / 128, M / 128);
        gemm_bf16_nt<<<g, 256, 0, stream>>>(AOb, Wob, out, nullptr, M, D, D, 0);
    }
}

// Round 4
// 221.293 us; speedup vs baseline: 6.3194x; 1.0782x over previous
//
#include <hip/hip_runtime.h>
#include <hip/hip_bf16.h>

// ---------------------------------------------------------------------------
// ALiBi MHA, windowed. B=2 T=2048 D=1024 H=16 d_k=64, window/2=128.
// Round 3: unified coalesced float4 prob-row writer (zeros + bf16->f32 probs
// from the LDS P tile), PV before the store stream, merged weight casts.
// ---------------------------------------------------------------------------

typedef __bf16 bf16x8 __attribute__((ext_vector_type(8)));
typedef float f32x4 __attribute__((ext_vector_type(4)));

__device__ __forceinline__ float bf2f(unsigned short u) {
    union { unsigned int i; float f; } v; v.i = ((unsigned int)u) << 16; return v.f;
}
__device__ __forceinline__ unsigned short f2bf(float f) {
    union { float f; unsigned int i; } v; v.f = f;
    unsigned int r = v.i + 0x7FFFu + ((v.i >> 16) & 1u);
    return (unsigned short)(r >> 16);
}

__global__ __launch_bounds__(256) void cast_kernel(const float* __restrict__ in,
                                                   unsigned short* __restrict__ out, int n) {
    int i = (blockIdx.x * 256 + threadIdx.x) * 4;
    if (i < n) {
        const float4 v = *(const float4*)(in + i);
        ushort4 o;
        o.x = f2bf(v.x); o.y = f2bf(v.y); o.z = f2bf(v.z); o.w = f2bf(v.w);
        *(ushort4*)(out + i) = o;
    }
}

// 4 weight matrices (1024x1024 each) -> contiguous bf16 dst
__global__ __launch_bounds__(256) void cast_w4(const float* __restrict__ a,
                                               const float* __restrict__ b,
                                               const float* __restrict__ c,
                                               const float* __restrict__ d,
                                               unsigned short* __restrict__ out) {
    const float* srcs[4] = {a, b, c, d};
    const float* src = srcs[blockIdx.y];
    const int i = (blockIdx.x * 256 + threadIdx.x) * 4;
    const float4 v = *(const float4*)(src + i);
    ushort4 o;
    o.x = f2bf(v.x); o.y = f2bf(v.y); o.z = f2bf(v.z); o.w = f2bf(v.w);
    *(ushort4*)(out + (size_t)blockIdx.y * 1048576 + i) = o;
}

#define GLDS16(g, l) __builtin_amdgcn_global_load_lds(                      \
    (const __attribute__((address_space(1))) void*)(g),                     \
    (__attribute__((address_space(3))) void*)(l), 16, 0, 0)

// C = A (MxK) * Bm^T (NxK); bf16 in, fp32 accum.
// mode 0: C fp32 row-major. mode 1: scatter bf16 QKV; V transposed (B,H,64,T).
__global__ __launch_bounds__(256) void gemm_bf16_nt(
    const unsigned short* __restrict__ A, const unsigned short* __restrict__ Bm,
    float* __restrict__ C, unsigned short* __restrict__ qkv,
    int M, int N, int K, int mode)
{
    __shared__ __align__(16) unsigned short As[128 * 32];
    __shared__ __align__(16) unsigned short Bs[128 * 32];

    const int tid  = threadIdx.x;
    const int lane = tid & 63, w = tid >> 6;
    const int bm = blockIdx.y * 128, bn = blockIdx.x * 128;

    const unsigned short* ga = A  + (size_t)(bm + w * 16 + (lane >> 2)) * K + (lane & 3) * 8;
    const unsigned short* gb = Bm + (size_t)(bn + w * 16 + (lane >> 2)) * K + (lane & 3) * 8;
    unsigned short* laA0 = &As[w * 512];
    unsigned short* laA1 = &As[2048 + w * 512];
    unsigned short* laB0 = &Bs[w * 512];
    unsigned short* laB1 = &Bs[2048 + w * 512];

    const int wr = w >> 1, wc = w & 1;
    const int fr = lane & 15, fq = lane >> 4;

    f32x4 acc[4][4] = {};

    for (int k0 = 0; k0 < K; k0 += 32) {
        GLDS16(ga + k0, laA0);
        GLDS16(ga + k0 + (size_t)64 * K, laA1);
        GLDS16(gb + k0, laB0);
        GLDS16(gb + k0 + (size_t)64 * K, laB1);
        __syncthreads();
        bf16x8 af[4], bfv[4];
#pragma unroll
        for (int i = 0; i < 4; ++i)
            af[i] = *(const bf16x8*)&As[(wr * 64 + i * 16 + fr) * 32 + fq * 8];
#pragma unroll
        for (int j = 0; j < 4; ++j)
            bfv[j] = *(const bf16x8*)&Bs[(wc * 64 + j * 16 + fr) * 32 + fq * 8];
#pragma unroll
        for (int i = 0; i < 4; ++i)
#pragma unroll
            for (int j = 0; j < 4; ++j)
                acc[i][j] = __builtin_amdgcn_mfma_f32_16x16x32_bf16(af[i], bfv[j], acc[i][j], 0, 0, 0);
        __syncthreads();
    }

#pragma unroll
    for (int i = 0; i < 4; ++i) {
#pragma unroll
        for (int j = 0; j < 4; ++j) {
            const int mb = bm + wr * 64 + i * 16 + fq * 4;
            const int n  = bn + wc * 64 + j * 16 + fr;
#pragma unroll
            for (int r = 0; r < 4; ++r) {
                const int m = mb + r;
                const float val = acc[i][j][r];
                if (mode == 0) {
                    C[(size_t)m * N + n] = val;
                } else {
                    const int which = n >> 10, hh = (n >> 6) & 15, dd = n & 63;
                    const int bb = m >> 11, tt = m & 2047;
                    size_t off;
                    if (which == 2)   // V transposed: (B,H,64,T)
                        off = (size_t)2 * 4194304 + (((size_t)bb * 16 + hh) * 64 + dd) * 2048 + tt;
                    else
                        off = (size_t)which * 4194304 + (((size_t)bb * 16 + hh) * 2048 + tt) * 64 + dd;
                    qkv[off] = f2bf(val);
                }
            }
        }
    }
}

// MFMA attention. Block = 64 q-rows of one head; 4 waves x 16 q-rows.
#define NT_MAX 20
__global__ __launch_bounds__(256) void attn_mfma(
    const unsigned short* __restrict__ Q, const unsigned short* __restrict__ K,
    const unsigned short* __restrict__ VT, float* __restrict__ attn,
    unsigned short* __restrict__ ao, const int* __restrict__ wptr)
{
    const int T = 2048;
    __shared__ __align__(16) unsigned short Plds[4][16][328];

    const int bid = (int)blockIdx.x;
    const int swz = (bid & 7) * 128 + (bid >> 3);      // XCD-contiguous
    const int w = threadIdx.x >> 6, lane = threadIdx.x & 63;
    const int fr = lane & 15, fq = lane >> 4;

    const int tblk = swz & 31;
    const int h    = (swz >> 5) & 15;
    const int b    = swz >> 9;
    const int t0   = tblk * 64;

    const int W2 = wptr[0] >> 1;                       // 128 (mult of 16)
    const int sA = (t0 - W2) > 0 ? (t0 - W2) : 0;
    int sB = t0 + 63 + W2; if (sB > T - 1) sB = T - 1;
    const int sEnd = sB + 1;                           // 16-aligned
    const int nt  = (sEnd - sA) >> 4;                  // 12..20 tiles
    const int ncc = (nt + 1) >> 1;                     // 32-wide PV chunks

    const size_t bhT = ((size_t)b * 16 + h) * T;
    const unsigned short* Qbh  = Q  + bhT * 64;
    const unsigned short* Kbh  = K  + bhT * 64;
    const unsigned short* VTbh = VT + (((size_t)b * 16 + h) * 64) * T;

    // ---- Q fragments (16 rows x 64) ----
    bf16x8 aq0 = *(const bf16x8*)(Qbh + (size_t)(t0 + w * 16 + fr) * 64 + fq * 8);
    bf16x8 aq1 = *(const bf16x8*)(Qbh + (size_t)(t0 + w * 16 + fr) * 64 + 32 + fq * 8);

    const float slope = exp2f(-0.5f * (float)(h + 1));
    const int trow0 = t0 + w * 16 + fq * 4;

    // ---- QK^T: up to 20 tiles of 16 keys ----
    f32x4 sc[NT_MAX];
#pragma unroll
    for (int st = 0; st < NT_MAX; ++st) {
        const int sbase = sA + st * 16;
        if (sbase < sEnd) {
            const unsigned short* kb = Kbh + (size_t)(sbase + fr) * 64 + fq * 8;
            bf16x8 b0 = *(const bf16x8*)(kb);
            bf16x8 b1 = *(const bf16x8*)(kb + 32);
            f32x4 sv = {0.f, 0.f, 0.f, 0.f};
            sv = __builtin_amdgcn_mfma_f32_16x16x32_bf16(aq0, b0, sv, 0, 0, 0);
            sv = __builtin_amdgcn_mfma_f32_16x16x32_bf16(aq1, b1, sv, 0, 0, 0);
            const int scol = sbase + fr;
#pragma unroll
            for (int rr = 0; rr < 4; ++rr) {
                const int d = trow0 + rr - scol;
                const int ad = d < 0 ? -d : d;
                const float val = sv[rr] * 0.125f - slope * (float)ad;
                sc[st][rr] = (ad <= W2) ? val : -1e30f;
            }
        } else {
            sc[st] = (f32x4){-1e30f, -1e30f, -1e30f, -1e30f};
        }
    }

    // ---- softmax per row (row spread over 16 fr-lanes) ----
    float inv[4];
#pragma unroll
    for (int rr = 0; rr < 4; ++rr) {
        float m = -1e30f;
#pragma unroll
        for (int st = 0; st < NT_MAX; ++st) m = fmaxf(m, sc[st][rr]);
#pragma unroll
        for (int off = 1; off < 16; off <<= 1) m = fmaxf(m, __shfl_xor(m, off, 64));
        float s = 0.f;
#pragma unroll
        for (int st = 0; st < NT_MAX; ++st) {
            const float p = __expf(sc[st][rr] - m);
            sc[st][rr] = p;
            s += p;
        }
#pragma unroll
        for (int off = 1; off < 16; off <<= 1) s += __shfl_xor(s, off, 64);
        inv[rr] = 1.0f / s;
    }

    // ---- stage normalized probs (bf16) into per-wave LDS tile ----
#pragma unroll
    for (int st = 0; st < NT_MAX; ++st) {
        const int sbase = sA + st * 16;
        if (sbase < sEnd) {
#pragma unroll
            for (int rr = 0; rr < 4; ++rr)
                Plds[w][fq * 4 + rr][st * 16 + fr] = f2bf(sc[st][rr] * inv[rr]);
        } else {
#pragma unroll
            for (int rr = 0; rr < 4; ++rr)
                Plds[w][fq * 4 + rr][st * 16 + fr] = 0;
        }
    }

    // ---- PV first (MFMA overlaps the later store stream) ----
    f32x4 oacc[4] = {};
    for (int c = 0; c < ncc; ++c) {
        const bf16x8 pa = *(const bf16x8*)&Plds[w][fr][c * 32 + fq * 8];
#pragma unroll
        for (int j = 0; j < 4; ++j) {
            const bf16x8 bv = *(const bf16x8*)(VTbh + (size_t)(j * 16 + fr) * T + sA + c * 32 + fq * 8);
            oacc[j] = __builtin_amdgcn_mfma_f32_16x16x32_bf16(pa, bv, oacc[j], 0, 0, 0);
        }
    }

    // ---- unified full-row writer: pure float4 stream, zeros + probs ----
    for (int i = 0; i < 16; ++i) {
        float* row = attn + (bhT + t0 + w * 16 + i) * T;
        const unsigned short* prow = &Plds[w][i][0];
#pragma unroll
        for (int it = 0; it < 8; ++it) {
            const int c = it * 256 + lane * 4;
            float4 v;
            if (c >= sA && c < sEnd) {
                const int pc = c - sA;
                v.x = bf2f(prow[pc + 0]);
                v.y = bf2f(prow[pc + 1]);
                v.z = bf2f(prow[pc + 2]);
                v.w = bf2f(prow[pc + 3]);
            } else {
                v.x = 0.f; v.y = 0.f; v.z = 0.f; v.w = 0.f;
            }
            *(float4*)(row + c) = v;
        }
    }

#pragma unroll
    for (int j = 0; j < 4; ++j)
#pragma unroll
        for (int rr = 0; rr < 4; ++rr)
            ao[((size_t)b * T + trow0 + rr) * 1024 + h * 64 + j * 16 + fr] = f2bf(oacc[j][rr]);
}

extern "C" void kernel_launch(void* const* d_in, const int* in_sizes, int n_in,
                              void* d_out, int out_size, void* d_ws, size_t ws_size,
                              hipStream_t stream)
{
    const float* x  = (const float*)d_in[0];
    const float* Wq = (const float*)d_in[1];
    const float* Wk = (const float*)d_in[2];
    const float* Wv = (const float*)d_in[3];
    const float* Wo = (const float*)d_in[4];
    const int*  win = (const int*)d_in[5];

    const int M = 4096, D = 1024;                 // M = B*T

    unsigned short* xb    = (unsigned short*)d_ws;            // 4096x1024
    unsigned short* Wqkvb = xb + (size_t)M * D;               // 3072x1024
    unsigned short* Wob   = Wqkvb + (size_t)3 * D * D;        // 1024x1024
    unsigned short* QKVb  = Wob + (size_t)D * D;              // Q,K,(V^T)
    unsigned short* AOb   = QKVb + (size_t)3 * M * D;         // 4096x1024

    float* out  = (float*)d_out;                  // (B,T,D)
    float* attn = out + (size_t)M * D;            // (B,H,T,T)

    cast_kernel<<<M * D / 1024, 256, 0, stream>>>(x, xb, M * D);
    {
        dim3 g(D * D / 1024, 4);
        cast_w4<<<g, 256, 0, stream>>>(Wq, Wk, Wv, Wo, Wqkvb);
    }

    {
        dim3 g(3072 / 128, M / 128);
        gemm_bf16_nt<<<g, 256, 0, stream>>>(xb, Wqkvb, nullptr, QKVb, M, 3072, D, 1);
    }

    attn_mfma<<<1024, 256, 0, stream>>>(
        QKVb, QKVb + (size_t)M * D, QKVb + (size_t)2 * M * D, attn, AOb, win);

    {
        dim3 g(D / 128, M / 128);
        gemm_bf16_nt<<<g, 256, 0, stream>>>(AOb, Wob, out, nullptr, M, D, D, 0);
    }
}

// Round 5
// 217.573 us; speedup vs baseline: 6.4274x; 1.0171x over previous
//
#include <hip/hip_runtime.h>
#include <hip/hip_bf16.h>

// ---------------------------------------------------------------------------
// ALiBi MHA, windowed. B=2 T=2048 D=1024 H=16 d_k=64, window/2=128.
// Round 4: attn store-pipeline restructure — dependency-free zero stores
// issued right after QK^T (before softmax), window stores before PV, so the
// 537 MB prob-write stream saturates HBM from early in the kernel.
// Casts merged into one launch.
// ---------------------------------------------------------------------------

typedef __bf16 bf16x8 __attribute__((ext_vector_type(8)));
typedef float f32x4 __attribute__((ext_vector_type(4)));

__device__ __forceinline__ float bf2f(unsigned short u) {
    union { unsigned int i; float f; } v; v.i = ((unsigned int)u) << 16; return v.f;
}
__device__ __forceinline__ unsigned short f2bf(float f) {
    union { float f; unsigned int i; } v; v.f = f;
    unsigned int r = v.i + 0x7FFFu + ((v.i >> 16) & 1u);
    return (unsigned short)(r >> 16);
}

// slice 0..3: x (4M elems, 1M per slice) -> xb ; slice 4..7: Wq/Wk/Wv/Wo -> wb
__global__ __launch_bounds__(256) void cast_all(
    const float* __restrict__ x,
    const float* __restrict__ wq, const float* __restrict__ wk,
    const float* __restrict__ wv, const float* __restrict__ wo,
    unsigned short* __restrict__ xb, unsigned short* __restrict__ wb)
{
    const int slice = blockIdx.y;
    const int i = (blockIdx.x * 256 + threadIdx.x) * 4;
    const float* src;
    unsigned short* dst;
    if (slice < 4) {
        src = x + (size_t)slice * 1048576;
        dst = xb + (size_t)slice * 1048576;
    } else {
        const float* ws4[4] = {wq, wk, wv, wo};
        src = ws4[slice - 4];
        dst = wb + (size_t)(slice - 4) * 1048576;
    }
    const float4 v = *(const float4*)(src + i);
    ushort4 o;
    o.x = f2bf(v.x); o.y = f2bf(v.y); o.z = f2bf(v.z); o.w = f2bf(v.w);
    *(ushort4*)(dst + i) = o;
}

#define GLDS16(g, l) __builtin_amdgcn_global_load_lds(                      \
    (const __attribute__((address_space(1))) void*)(g),                     \
    (__attribute__((address_space(3))) void*)(l), 16, 0, 0)

// C = A (MxK) * Bm^T (NxK); bf16 in, fp32 accum.
// mode 0: C fp32 row-major. mode 1: scatter bf16 QKV; V transposed (B,H,64,T).
__global__ __launch_bounds__(256) void gemm_bf16_nt(
    const unsigned short* __restrict__ A, const unsigned short* __restrict__ Bm,
    float* __restrict__ C, unsigned short* __restrict__ qkv,
    int M, int N, int K, int mode)
{
    __shared__ __align__(16) unsigned short As[128 * 32];
    __shared__ __align__(16) unsigned short Bs[128 * 32];

    const int tid  = threadIdx.x;
    const int lane = tid & 63, w = tid >> 6;
    const int bm = blockIdx.y * 128, bn = blockIdx.x * 128;

    const unsigned short* ga = A  + (size_t)(bm + w * 16 + (lane >> 2)) * K + (lane & 3) * 8;
    const unsigned short* gb = Bm + (size_t)(bn + w * 16 + (lane >> 2)) * K + (lane & 3) * 8;
    unsigned short* laA0 = &As[w * 512];
    unsigned short* laA1 = &As[2048 + w * 512];
    unsigned short* laB0 = &Bs[w * 512];
    unsigned short* laB1 = &Bs[2048 + w * 512];

    const int wr = w >> 1, wc = w & 1;
    const int fr = lane & 15, fq = lane >> 4;

    f32x4 acc[4][4] = {};

    for (int k0 = 0; k0 < K; k0 += 32) {
        GLDS16(ga + k0, laA0);
        GLDS16(ga + k0 + (size_t)64 * K, laA1);
        GLDS16(gb + k0, laB0);
        GLDS16(gb + k0 + (size_t)64 * K, laB1);
        __syncthreads();
        bf16x8 af[4], bfv[4];
#pragma unroll
        for (int i = 0; i < 4; ++i)
            af[i] = *(const bf16x8*)&As[(wr * 64 + i * 16 + fr) * 32 + fq * 8];
#pragma unroll
        for (int j = 0; j < 4; ++j)
            bfv[j] = *(const bf16x8*)&Bs[(wc * 64 + j * 16 + fr) * 32 + fq * 8];
#pragma unroll
        for (int i = 0; i < 4; ++i)
#pragma unroll
            for (int j = 0; j < 4; ++j)
                acc[i][j] = __builtin_amdgcn_mfma_f32_16x16x32_bf16(af[i], bfv[j], acc[i][j], 0, 0, 0);
        __syncthreads();
    }

#pragma unroll
    for (int i = 0; i < 4; ++i) {
#pragma unroll
        for (int j = 0; j < 4; ++j) {
            const int mb = bm + wr * 64 + i * 16 + fq * 4;
            const int n  = bn + wc * 64 + j * 16 + fr;
#pragma unroll
            for (int r = 0; r < 4; ++r) {
                const int m = mb + r;
                const float val = acc[i][j][r];
                if (mode == 0) {
                    C[(size_t)m * N + n] = val;
                } else {
                    const int which = n >> 10, hh = (n >> 6) & 15, dd = n & 63;
                    const int bb = m >> 11, tt = m & 2047;
                    size_t off;
                    if (which == 2)   // V transposed: (B,H,64,T)
                        off = (size_t)2 * 4194304 + (((size_t)bb * 16 + hh) * 64 + dd) * 2048 + tt;
                    else
                        off = (size_t)which * 4194304 + (((size_t)bb * 16 + hh) * 2048 + tt) * 64 + dd;
                    qkv[off] = f2bf(val);
                }
            }
        }
    }
}

// MFMA attention. Block = 64 q-rows of one head; 4 waves x 16 q-rows.
// Store pipeline: QK^T -> zero-stores -> softmax -> stage -> window-stores
// -> PV -> AO. Zero stores are issued AFTER the K loads (in-order vmcnt
// retirement keeps compute waits from draining the store queue).
#define NT_MAX 20
__global__ __launch_bounds__(256) void attn_mfma(
    const unsigned short* __restrict__ Q, const unsigned short* __restrict__ K,
    const unsigned short* __restrict__ VT, float* __restrict__ attn,
    unsigned short* __restrict__ ao, const int* __restrict__ wptr)
{
    const int T = 2048;
    __shared__ __align__(16) unsigned short Plds[4][16][328];

    const int bid = (int)blockIdx.x;
    const int swz = (bid & 7) * 128 + (bid >> 3);      // XCD-contiguous
    const int w = threadIdx.x >> 6, lane = threadIdx.x & 63;
    const int fr = lane & 15, fq = lane >> 4;

    const int tblk = swz & 31;
    const int h    = (swz >> 5) & 15;
    const int b    = swz >> 9;
    const int t0   = tblk * 64;

    const int W2 = wptr[0] >> 1;                       // 128 (mult of 16)
    const int sA = (t0 - W2) > 0 ? (t0 - W2) : 0;
    int sB = t0 + 63 + W2; if (sB > T - 1) sB = T - 1;
    const int sEnd = sB + 1;                           // 16-aligned
    const int nt  = (sEnd - sA) >> 4;                  // 12..20 tiles (even)
    const int ncc = (nt + 1) >> 1;                     // 32-wide PV chunks

    const size_t bhT = ((size_t)b * 16 + h) * T;
    const unsigned short* Qbh  = Q  + bhT * 64;
    const unsigned short* Kbh  = K  + bhT * 64;
    const unsigned short* VTbh = VT + (((size_t)b * 16 + h) * 64) * T;

    // ---- Q fragments (16 rows x 64) ----
    bf16x8 aq0 = *(const bf16x8*)(Qbh + (size_t)(t0 + w * 16 + fr) * 64 + fq * 8);
    bf16x8 aq1 = *(const bf16x8*)(Qbh + (size_t)(t0 + w * 16 + fr) * 64 + 32 + fq * 8);

    const float slope = exp2f(-0.5f * (float)(h + 1));
    const int trow0 = t0 + w * 16 + fq * 4;

    // ---- QK^T: up to 20 tiles of 16 keys ----
    f32x4 sc[NT_MAX];
#pragma unroll
    for (int st = 0; st < NT_MAX; ++st) {
        const int sbase = sA + st * 16;
        if (sbase < sEnd) {
            const unsigned short* kb = Kbh + (size_t)(sbase + fr) * 64 + fq * 8;
            bf16x8 b0 = *(const bf16x8*)(kb);
            bf16x8 b1 = *(const bf16x8*)(kb + 32);
            f32x4 sv = {0.f, 0.f, 0.f, 0.f};
            sv = __builtin_amdgcn_mfma_f32_16x16x32_bf16(aq0, b0, sv, 0, 0, 0);
            sv = __builtin_amdgcn_mfma_f32_16x16x32_bf16(aq1, b1, sv, 0, 0, 0);
            const int scol = sbase + fr;
#pragma unroll
            for (int rr = 0; rr < 4; ++rr) {
                const int d = trow0 + rr - scol;
                const int ad = d < 0 ? -d : d;
                const float val = sv[rr] * 0.125f - slope * (float)ad;
                sc[st][rr] = (ad <= W2) ? val : -1e30f;
            }
        } else {
            sc[st] = (f32x4){-1e30f, -1e30f, -1e30f, -1e30f};
        }
    }

    // ---- dependency-free zero stores (84% of row bytes) — issue early ----
    {
        const float4 z4 = {0.f, 0.f, 0.f, 0.f};
        for (int i = 0; i < 16; ++i) {
            float* row = attn + (bhT + t0 + w * 16 + i) * T;
            for (int c = lane * 4; c < sA; c += 256) *(float4*)(row + c) = z4;
            for (int c = sEnd + lane * 4; c < T; c += 256) *(float4*)(row + c) = z4;
        }
    }

    // ---- softmax per row (row spread over 16 fr-lanes); stores drain ----
    float inv[4];
#pragma unroll
    for (int rr = 0; rr < 4; ++rr) {
        float m = -1e30f;
#pragma unroll
        for (int st = 0; st < NT_MAX; ++st) m = fmaxf(m, sc[st][rr]);
#pragma unroll
        for (int off = 1; off < 16; off <<= 1) m = fmaxf(m, __shfl_xor(m, off, 64));
        float s = 0.f;
#pragma unroll
        for (int st = 0; st < NT_MAX; ++st) {
            const float p = __expf(sc[st][rr] - m);
            sc[st][rr] = p;
            s += p;
        }
#pragma unroll
        for (int off = 1; off < 16; off <<= 1) s += __shfl_xor(s, off, 64);
        inv[rr] = 1.0f / s;
    }

    // ---- stage normalized probs (bf16) into per-wave LDS tile ----
#pragma unroll
    for (int st = 0; st < NT_MAX; ++st) {
        const int sbase = sA + st * 16;
        if (sbase < sEnd) {
#pragma unroll
            for (int rr = 0; rr < 4; ++rr)
                Plds[w][fq * 4 + rr][st * 16 + fr] = f2bf(sc[st][rr] * inv[rr]);
        } else {
#pragma unroll
            for (int rr = 0; rr < 4; ++rr)
                Plds[w][fq * 4 + rr][st * 16 + fr] = 0;
        }
    }

    // ---- in-window prob stores (float4, coalesced) ----
    for (int i = 0; i < 16; ++i) {
        float* row = attn + (bhT + t0 + w * 16 + i) * T;
        const unsigned short* prow = &Plds[w][i][0];
#pragma unroll
        for (int jj = 0; jj < 2; ++jj) {           // 2*64*4 = 512 >= 320 cols
            const int pc = (jj * 64 + lane) * 4;
            const int c = sA + pc;
            if (c < sEnd) {
                float4 v;
                v.x = bf2f(prow[pc + 0]);
                v.y = bf2f(prow[pc + 1]);
                v.z = bf2f(prow[pc + 2]);
                v.w = bf2f(prow[pc + 3]);
                *(float4*)(row + c) = v;
            }
        }
    }

    // ---- PV: out[16q x 64d] = P[16 x nt*16] x V[nt*16 x 64] ----
    f32x4 oacc[4] = {};
    for (int c = 0; c < ncc; ++c) {
        const bf16x8 pa = *(const bf16x8*)&Plds[w][fr][c * 32 + fq * 8];
#pragma unroll
        for (int j = 0; j < 4; ++j) {
            const bf16x8 bv = *(const bf16x8*)(VTbh + (size_t)(j * 16 + fr) * T + sA + c * 32 + fq * 8);
            oacc[j] = __builtin_amdgcn_mfma_f32_16x16x32_bf16(pa, bv, oacc[j], 0, 0, 0);
        }
    }

#pragma unroll
    for (int j = 0; j < 4; ++j)
#pragma unroll
        for (int rr = 0; rr < 4; ++rr)
            ao[((size_t)b * T + trow0 + rr) * 1024 + h * 64 + j * 16 + fr] = f2bf(oacc[j][rr]);
}

extern "C" void kernel_launch(void* const* d_in, const int* in_sizes, int n_in,
                              void* d_out, int out_size, void* d_ws, size_t ws_size,
                              hipStream_t stream)
{
    const float* x  = (const float*)d_in[0];
    const float* Wq = (const float*)d_in[1];
    const float* Wk = (const float*)d_in[2];
    const float* Wv = (const float*)d_in[3];
    const float* Wo = (const float*)d_in[4];
    const int*  win = (const int*)d_in[5];

    const int M = 4096, D = 1024;                 // M = B*T

    unsigned short* xb    = (unsigned short*)d_ws;            // 4096x1024
    unsigned short* Wqkvb = xb + (size_t)M * D;               // 3072x1024
    unsigned short* Wob   = Wqkvb + (size_t)3 * D * D;        // 1024x1024
    unsigned short* QKVb  = Wob + (size_t)D * D;              // Q,K,(V^T)
    unsigned short* AOb   = QKVb + (size_t)3 * M * D;         // 4096x1024

    float* out  = (float*)d_out;                  // (B,T,D)
    float* attn = out + (size_t)M * D;            // (B,H,T,T)

    {
        dim3 g(1024, 8);
        cast_all<<<g, 256, 0, stream>>>(x, Wq, Wk, Wv, Wo, xb, Wqkvb);
    }

    {
        dim3 g(3072 / 128, M / 128);
        gemm_bf16_nt<<<g, 256, 0, stream>>>(xb, Wqkvb, nullptr, QKVb, M, 3072, D, 1);
    }

    attn_mfma<<<1024, 256, 0, stream>>>(
        QKVb, QKVb + (size_t)M * D, QKVb + (size_t)2 * M * D, attn, AOb, win);

    {
        dim3 g(D / 128, M / 128);
        gemm_bf16_nt<<<g, 256, 0, stream>>>(AOb, Wob, out, nullptr, M, D, D, 0);
    }
}